// Round 1
// baseline (4887.263 us; speedup 1.0000x reference)
//
#include <hip/hip_runtime.h>
#include <hip/hip_bf16.h>
#include <stdint.h>

// LinearAttentionBlock: B=2,T=4096,D=1024,H=8,DK=DV=128,INTER=4096,CHUNK=128
// Round 1: correctness-first full pipeline. bf16 MFMA GEMMs (128x128 tile,
// padded LDS, reg-staged), VALU f32 attention chunk kernels, fused epilogues.

typedef __hip_bfloat16 bf16;
typedef __bf16 bf16x8 __attribute__((ext_vector_type(8)));
typedef float f32x4 __attribute__((ext_vector_type(4)));

union Frag {
  uint4 u;
  bf16x8 b;
  unsigned short s[8];
};

__device__ __forceinline__ float bf2f(unsigned short v) {
  union { unsigned int u; float f; } c;
  c.u = (unsigned int)v << 16;
  return c.f;
}
__device__ __forceinline__ unsigned short f2bf(float f) {
  union { float f; unsigned int u; } c;
  c.f = f;
  unsigned int u = c.u;
  u += 0x7fffu + ((u >> 16) & 1u);
  return (unsigned short)(u >> 16);
}

// ---------------- RMSNorm: f32 [rows][1024] -> bf16, block=256, grid=rows ----
__global__ __launch_bounds__(256) void k_rmsnorm(const float* __restrict__ x,
                                                 const float* __restrict__ w,
                                                 bf16* __restrict__ out) {
  const int row = blockIdx.x;
  const int t = threadIdx.x;
  float4 v = reinterpret_cast<const float4*>(x + (size_t)row * 1024)[t];
  float ss = v.x * v.x + v.y * v.y + v.z * v.z + v.w * v.w;
#pragma unroll
  for (int o = 32; o > 0; o >>= 1) ss += __shfl_xor(ss, o, 64);
  __shared__ float red[4];
  if ((t & 63) == 0) red[t >> 6] = ss;
  __syncthreads();
  float tot = red[0] + red[1] + red[2] + red[3];
  float sc = rsqrtf(tot * (1.f / 1024.f) + 1e-5f);
  float4 wv = reinterpret_cast<const float4*>(w)[t];
  ushort4 o4;
  o4.x = f2bf(v.x * sc * wv.x);
  o4.y = f2bf(v.y * sc * wv.y);
  o4.z = f2bf(v.z * sc * wv.z);
  o4.w = f2bf(v.w * sc * wv.w);
  reinterpret_cast<ushort4*>(out + (size_t)row * 1024)[t] = o4;
}

// ------------- Weight transpose+convert: f32 [R][C] -> bf16 [C][R] ----------
__global__ __launch_bounds__(256) void k_transpose_w(const float* __restrict__ W,
                                                     bf16* __restrict__ WT,
                                                     int R, int C) {
  __shared__ float tile[32][33];
  const int bx = blockIdx.x * 32;  // C
  const int by = blockIdx.y * 32;  // R
  const int tx = threadIdx.x, ty = threadIdx.y;  // (32,8)
#pragma unroll
  for (int i = 0; i < 4; i++)
    tile[ty + i * 8][tx] = W[(size_t)(by + ty + i * 8) * C + bx + tx];
  __syncthreads();
  unsigned short* WTu = (unsigned short*)WT;
#pragma unroll
  for (int i = 0; i < 4; i++)
    WTu[(size_t)(bx + ty + i * 8) * R + by + tx] = f2bf(tile[tx][ty + i * 8]);
}

// ---------------- GEMM: C[M,N] = A[M,K](bf16) x BT[N,K](bf16) ----------------
// 128x128 tile, BK=64, 256 thr (4 waves, 2x2 of 64x64), mfma 16x16x32 bf16.
// EPI: 0 = store bf16; 1 = f32 store + residual add; 2 = silu(existing)*acc.
template <int EPI>
__global__ __launch_bounds__(256) void k_gemm(const bf16* __restrict__ A, int lda,
                                              const bf16* __restrict__ BT,
                                              const float* __restrict__ res,
                                              void* __restrict__ Cout,
                                              int N, int K) {
  constexpr int BK = 64;
  __shared__ __align__(16) unsigned short As[128][BK + 8];
  __shared__ __align__(16) unsigned short Bs[128][BK + 8];
  const int bm = blockIdx.y * 128, bn = blockIdx.x * 128;
  const int t = threadIdx.x;
  const int wid = t >> 6, lane = t & 63;
  const int wm = (wid >> 1) * 64, wn = (wid & 1) * 64;
  const int lm = lane & 15, kg = lane >> 4;

  const unsigned short* Ab = (const unsigned short*)A;
  const unsigned short* Bb = (const unsigned short*)BT;

  f32x4 acc[4][4] = {};
  uint4 areg[4], breg[4];
  const int r0 = t >> 3;           // + i*32
  const int c8 = (t & 7) << 3;     // element col within BK

#pragma unroll
  for (int i = 0; i < 4; i++) {
    areg[i] = *reinterpret_cast<const uint4*>(Ab + (size_t)(bm + r0 + i * 32) * lda + c8);
    breg[i] = *reinterpret_cast<const uint4*>(Bb + (size_t)(bn + r0 + i * 32) * K + c8);
  }
  const int NT = K / BK;
  for (int kt = 0; kt < NT; kt++) {
    __syncthreads();
#pragma unroll
    for (int i = 0; i < 4; i++) {
      *reinterpret_cast<uint4*>(&As[r0 + i * 32][c8]) = areg[i];
      *reinterpret_cast<uint4*>(&Bs[r0 + i * 32][c8]) = breg[i];
    }
    __syncthreads();
    if (kt + 1 < NT) {
      const int ko = (kt + 1) * BK;
#pragma unroll
      for (int i = 0; i < 4; i++) {
        areg[i] = *reinterpret_cast<const uint4*>(Ab + (size_t)(bm + r0 + i * 32) * lda + ko + c8);
        breg[i] = *reinterpret_cast<const uint4*>(Bb + (size_t)(bn + r0 + i * 32) * K + ko + c8);
      }
    }
#pragma unroll
    for (int kk = 0; kk < 2; kk++) {
      Frag af[4], bfr[4];
#pragma unroll
      for (int i = 0; i < 4; i++) {
        af[i].u = *reinterpret_cast<const uint4*>(&As[wm + i * 16 + lm][kk * 32 + kg * 8]);
        bfr[i].u = *reinterpret_cast<const uint4*>(&Bs[wn + i * 16 + lm][kk * 32 + kg * 8]);
      }
#pragma unroll
      for (int mi = 0; mi < 4; mi++)
#pragma unroll
        for (int ni = 0; ni < 4; ni++)
          acc[mi][ni] = __builtin_amdgcn_mfma_f32_16x16x32_bf16(af[mi].b, bfr[ni].b,
                                                                acc[mi][ni], 0, 0, 0);
    }
  }
  // epilogue: C row = bm+wm+mi*16+kg*4+r ; col = bn+wn+ni*16+lm
#pragma unroll
  for (int mi = 0; mi < 4; mi++) {
#pragma unroll
    for (int r = 0; r < 4; r++) {
      const int row = bm + wm + mi * 16 + kg * 4 + r;
#pragma unroll
      for (int ni = 0; ni < 4; ni++) {
        const int col = bn + wn + ni * 16 + lm;
        float v = acc[mi][ni][r];
        const size_t o = (size_t)row * N + col;
        if constexpr (EPI == 0) {
          ((unsigned short*)Cout)[o] = f2bf(v);
        } else if constexpr (EPI == 1) {
          ((float*)Cout)[o] = v + res[o];
        } else {
          unsigned short* cp = (unsigned short*)Cout;
          float g = bf2f(cp[o]);
          float sg = g / (1.f + __expf(-g));
          cp[o] = f2bf(sg * v);
        }
      }
    }
  }
}

// -------- K_A: per-(b,h,chunk) G = k^T v (f32, VALU). grid=512, 256 thr -----
__global__ __launch_bounds__(256) void k_chunk_kv(const bf16* __restrict__ qkv,
                                                  float* __restrict__ G) {
  __shared__ __align__(16) unsigned short ks[128][128];
  __shared__ __align__(16) unsigned short vs[128][128];
  const int idx = blockIdx.x;
  const int cc = idx & 31, bh = idx >> 5, bb = bh >> 3, hh = bh & 7;
  const unsigned short* qkvu = (const unsigned short*)qkv;
  const unsigned short* kp = qkvu + (size_t)(bb * 4096 + cc * 128) * 3072 + 1024 + hh * 128;
  const unsigned short* vp = kp + 1024;
  const int t = threadIdx.x;
#pragma unroll
  for (int i = 0; i < 8; i++) {
    int ch = t + i * 256;
    int r = ch >> 4, c8 = (ch & 15) << 3;
    *(uint4*)&ks[r][c8] = *(const uint4*)(kp + (size_t)r * 3072 + c8);
    *(uint4*)&vs[r][c8] = *(const uint4*)(vp + (size_t)r * 3072 + c8);
  }
  __syncthreads();
  const int dk0 = (t >> 4) * 8, dv0 = (t & 15) * 8;
  float acc[8][8] = {};
  for (int j = 0; j < 128; j++) {
    Frag kf, vf;
    kf.u = *(const uint4*)&ks[j][dk0];
    vf.u = *(const uint4*)&vs[j][dv0];
    float kx[8], vx[8];
#pragma unroll
    for (int a = 0; a < 8; a++) { kx[a] = bf2f(kf.s[a]); vx[a] = bf2f(vf.s[a]); }
#pragma unroll
    for (int a = 0; a < 8; a++)
#pragma unroll
      for (int b2 = 0; b2 < 8; b2++) acc[a][b2] += kx[a] * vx[b2];
  }
  float* Gp = G + (size_t)idx * 16384;
#pragma unroll
  for (int a = 0; a < 8; a++)
#pragma unroll
    for (int b2 = 0; b2 < 8; b2 += 4) {
      float4 w4 = make_float4(acc[a][b2], acc[a][b2 + 1], acc[a][b2 + 2], acc[a][b2 + 3]);
      *(float4*)(Gp + (size_t)(dk0 + a) * 128 + dv0 + b2) = w4;
    }
}

// -------- K_B: exclusive prefix over chunks -> S bf16. grid=1024 ------------
__global__ __launch_bounds__(256) void k_prefix(const float* __restrict__ G,
                                                bf16* __restrict__ S) {
  const size_t gid = (size_t)blockIdx.x * 256 + threadIdx.x;
  const size_t bh = gid >> 14, e = gid & 16383;
  const float* gp = G + (bh << 5) * 16384 + e;
  unsigned short* sp = (unsigned short*)S + (bh << 5) * 16384 + e;
  float run = 0.f;
  for (int c2 = 0; c2 < 32; c2++) {
    sp[(size_t)c2 << 14] = f2bf(run);
    run += gp[(size_t)c2 << 14];
  }
}

// -------- K_C: o = tril(q k^T) v + q S ; per-head RMSNorm; -> A2 bf16 --------
// grid=512, 256 thr. q,k/P in XOR-swizzled LDS; v,S streamed from L2.
__global__ __launch_bounds__(256) void k_chunk_attn(const bf16* __restrict__ qkv,
                                                    const bf16* __restrict__ S,
                                                    const float* __restrict__ nw,
                                                    bf16* __restrict__ A2) {
  __shared__ __align__(16) unsigned short qs[128][128];
  __shared__ __align__(16) unsigned short ps[128][128];
  const int idx = blockIdx.x;
  const int cc = idx & 31, bh = idx >> 5, bb = bh >> 3, hh = bh & 7;
  const size_t rowbase = (size_t)(bb * 4096 + cc * 128);
  const unsigned short* qkvu = (const unsigned short*)qkv;
  const unsigned short* qp = qkvu + rowbase * 3072 + hh * 128;
  const unsigned short* vp = qp + 2048;
  const unsigned short* Sp = (const unsigned short*)S + (size_t)idx * 16384;
  const int t = threadIdx.x;

  // stage q,k swizzled: chunk' = chunk ^ ((row>>3)&7)
#pragma unroll
  for (int i = 0; i < 8; i++) {
    int ch = t + i * 256;
    int r = ch >> 4, ck = ch & 15;
    int pc = (ck ^ ((r >> 3) & 7)) << 3;
    *(uint4*)&qs[r][pc] = *(const uint4*)(qp + (size_t)r * 3072 + (ck << 3));
    *(uint4*)&ps[r][pc] = *(const uint4*)(qp + 1024 + (size_t)r * 3072 + (ck << 3));
  }
  __syncthreads();

  const int i0 = (t >> 4) * 8, j0 = (t & 15) * 8;
  float acc[8][8] = {};
#pragma unroll
  for (int dkc = 0; dkc < 128; dkc += 8) {
    float kv[8][8];
#pragma unroll
    for (int jj = 0; jj < 8; jj++) {
      int row = j0 + jj;
      int pc = ((dkc >> 3) ^ ((row >> 3) & 7)) << 3;
      Frag f;
      f.u = *(const uint4*)&ps[row][pc];
#pragma unroll
      for (int a = 0; a < 8; a++) kv[jj][a] = bf2f(f.s[a]);
    }
#pragma unroll
    for (int ii = 0; ii < 8; ii++) {
      int row = i0 + ii;
      int pc = ((dkc >> 3) ^ ((row >> 3) & 7)) << 3;
      Frag f;
      f.u = *(const uint4*)&qs[row][pc];
      float qv[8];
#pragma unroll
      for (int a = 0; a < 8; a++) qv[a] = bf2f(f.s[a]);
#pragma unroll
      for (int jj = 0; jj < 8; jj++)
#pragma unroll
        for (int a = 0; a < 8; a++) acc[ii][jj] += qv[a] * kv[jj][a];
    }
  }
  __syncthreads();
  // masked P (bf16) -> ps
#pragma unroll
  for (int ii = 0; ii < 8; ii++) {
    int gi = i0 + ii;
    int pc = ((j0 >> 3) ^ ((gi >> 3) & 7)) << 3;
    Frag f;
#pragma unroll
    for (int jj = 0; jj < 8; jj++) f.s[jj] = f2bf((j0 + jj <= gi) ? acc[ii][jj] : 0.f);
    *(uint4*)&ps[gi][pc] = f.u;
  }
  __syncthreads();

  const int dv0 = j0;
  float oa[8][8] = {};
  // P @ V (V via L2)
#pragma unroll
  for (int jc = 0; jc < 128; jc += 8) {
    float vv[8][8];
#pragma unroll
    for (int jj = 0; jj < 8; jj++) {
      Frag f;
      f.u = *(const uint4*)(vp + (size_t)(jc + jj) * 3072 + dv0);
#pragma unroll
      for (int a = 0; a < 8; a++) vv[jj][a] = bf2f(f.s[a]);
    }
#pragma unroll
    for (int ii = 0; ii < 8; ii++) {
      int row = i0 + ii;
      int pc = ((jc >> 3) ^ ((row >> 3) & 7)) << 3;
      Frag f;
      f.u = *(const uint4*)&ps[row][pc];
#pragma unroll
      for (int jj = 0; jj < 8; jj++) {
        float pb = bf2f(f.s[jj]);
#pragma unroll
        for (int a = 0; a < 8; a++) oa[ii][a] += pb * vv[jj][a];
      }
    }
  }
  // Q @ S (S via L2)
#pragma unroll
  for (int kc = 0; kc < 128; kc += 8) {
    float sv[8][8];
#pragma unroll
    for (int kk = 0; kk < 8; kk++) {
      Frag f;
      f.u = *(const uint4*)(Sp + (size_t)(kc + kk) * 128 + dv0);
#pragma unroll
      for (int a = 0; a < 8; a++) sv[kk][a] = bf2f(f.s[a]);
    }
#pragma unroll
    for (int ii = 0; ii < 8; ii++) {
      int row = i0 + ii;
      int pc = ((kc >> 3) ^ ((row >> 3) & 7)) << 3;
      Frag f;
      f.u = *(const uint4*)&qs[row][pc];
#pragma unroll
      for (int kk = 0; kk < 8; kk++) {
        float qb = bf2f(f.s[kk]);
#pragma unroll
        for (int a = 0; a < 8; a++) oa[ii][a] += qb * sv[kk][a];
      }
    }
  }
  // per-row RMSNorm over DV=128 (16-lane group reduce) + write to A2
  float wv[8];
#pragma unroll
  for (int a = 0; a < 8; a++) wv[a] = nw[dv0 + a];
  unsigned short* A2u = (unsigned short*)A2;
#pragma unroll
  for (int ii = 0; ii < 8; ii++) {
    float ss = 0.f;
#pragma unroll
    for (int a = 0; a < 8; a++) ss += oa[ii][a] * oa[ii][a];
    ss += __shfl_xor(ss, 1, 64);
    ss += __shfl_xor(ss, 2, 64);
    ss += __shfl_xor(ss, 4, 64);
    ss += __shfl_xor(ss, 8, 64);
    float sc = rsqrtf(ss * (1.f / 128.f) + 1e-5f);
    Frag f;
#pragma unroll
    for (int a = 0; a < 8; a++) f.s[a] = f2bf(oa[ii][a] * sc * wv[a]);
    *(uint4*)(A2u + (rowbase + i0 + ii) * 1024 + hh * 128 + dv0) = f.u;
  }
}

// ---------------------------------------------------------------------------
extern "C" void kernel_launch(void* const* d_in, const int* in_sizes, int n_in,
                              void* d_out, int out_size, void* d_ws, size_t ws_size,
                              hipStream_t stream) {
  const float* x = (const float*)d_in[0];
  const float* anw = (const float*)d_in[1];
  const float* Wq = (const float*)d_in[2];
  const float* Wk = (const float*)d_in[3];
  const float* Wv = (const float*)d_in[4];
  const float* Wo = (const float*)d_in[5];
  const float* onw = (const float*)d_in[6];
  const float* mnw = (const float*)d_in[7];
  const float* Wg = (const float*)d_in[8];
  const float* Wu = (const float*)d_in[9];
  const float* Wd = (const float*)d_in[10];
  float* out = (float*)d_out;

  char* base = (char*)d_ws;
  size_t off = 0;
  auto alloc = [&](size_t bytes) -> char* {
    char* q = base + off;
    off += (bytes + 255) & ~(size_t)255;
    return q;
  };
  bf16* WqkvT = (bf16*)alloc(3072ll * 1024 * 2);   // [3072][1024]
  bf16* WoT   = (bf16*)alloc(1024ll * 1024 * 2);   // [1024][1024]
  bf16* WguT  = (bf16*)alloc(8192ll * 1024 * 2);   // [8192][1024] (gate|up)
  bf16* WdT   = (bf16*)alloc(1024ll * 4096 * 2);   // [1024][4096]
  bf16* h     = (bf16*)alloc(8192ll * 1024 * 2);   // normed acts / A2
  float* x1   = (float*)alloc(8192ll * 1024 * 4);  // residual stream after attn
  char* pool  = alloc(8192ll * 3072 * 2 + 16ll * 32 * 16384 * 4 + 16ll * 32 * 16384 * 2);
  bf16* qkv = (bf16*)pool;                                        // 50.3 MB
  float* G  = (float*)(pool + 8192ll * 3072 * 2);                 // 33.6 MB
  bf16* S   = (bf16*)(pool + 8192ll * 3072 * 2 + 16ll * 32 * 16384 * 4);  // 16.8 MB
  bf16* gate = (bf16*)pool;  // phase 2 reuse: [8192][4096] = 67 MB

  const dim3 tb32(32, 8);
  // weight transpose+convert
  k_transpose_w<<<dim3(32, 32), tb32, 0, stream>>>(Wq, WqkvT, 1024, 1024);
  k_transpose_w<<<dim3(32, 32), tb32, 0, stream>>>(Wk, WqkvT + 1024ll * 1024, 1024, 1024);
  k_transpose_w<<<dim3(32, 32), tb32, 0, stream>>>(Wv, WqkvT + 2048ll * 1024, 1024, 1024);
  k_transpose_w<<<dim3(32, 32), tb32, 0, stream>>>(Wo, WoT, 1024, 1024);
  k_transpose_w<<<dim3(128, 32), tb32, 0, stream>>>(Wg, WguT, 1024, 4096);
  k_transpose_w<<<dim3(128, 32), tb32, 0, stream>>>(Wu, WguT + 4096ll * 1024, 1024, 4096);
  k_transpose_w<<<dim3(32, 128), tb32, 0, stream>>>(Wd, WdT, 4096, 1024);

  // attn sub-block
  k_rmsnorm<<<8192, 256, 0, stream>>>(x, anw, h);
  k_gemm<0><<<dim3(24, 64), 256, 0, stream>>>(h, 1024, WqkvT, nullptr, qkv, 3072, 1024);
  k_chunk_kv<<<512, 256, 0, stream>>>(qkv, G);
  k_prefix<<<1024, 256, 0, stream>>>(G, S);
  k_chunk_attn<<<512, 256, 0, stream>>>(qkv, S, onw, h);  // h now = normed o, [8192][1024]
  k_gemm<1><<<dim3(8, 64), 256, 0, stream>>>(h, 1024, WoT, x, x1, 1024, 1024);

  // mlp sub-block
  k_rmsnorm<<<8192, 256, 0, stream>>>(x1, mnw, h);
  k_gemm<0><<<dim3(32, 64), 256, 0, stream>>>(h, 1024, WguT, nullptr, gate, 4096, 1024);
  k_gemm<2><<<dim3(32, 64), 256, 0, stream>>>(h, 1024, WguT + 4096ll * 1024, nullptr, gate, 4096, 1024);
  k_gemm<1><<<dim3(8, 64), 256, 0, stream>>>(gate, 4096, WdT, x1, out, 1024, 4096);
}

// Round 2
// 1489.265 us; speedup vs baseline: 3.2817x; 3.2817x over previous
//
#include <hip/hip_runtime.h>
#include <hip/hip_bf16.h>
#include <stdint.h>

// LinearAttentionBlock: B=2,T=4096,D=1024,H=8,DK=DV=128,INTER=4096,CHUNK=128
// Round 2: MFMA chunk attention (fixes 3.5ms register-spill VALU kernel).
// - k_attn2: per (b,h,chunk) fused P=tril(QK^T), O=PV+QS, per-head RMSNorm.
// - V^T materialized globally (tiled transpose); k_chunk_kv emits G^T so the
//   chunk prefix produces S^T -> all MFMA B-operands are K-contiguous.

typedef __hip_bfloat16 bf16;
typedef __bf16 bf16x8 __attribute__((ext_vector_type(8)));
typedef float f32x4 __attribute__((ext_vector_type(4)));

union Frag {
  uint4 u;
  bf16x8 b;
  unsigned short s[8];
};

__device__ __forceinline__ float bf2f(unsigned short v) {
  union { unsigned int u; float f; } c;
  c.u = (unsigned int)v << 16;
  return c.f;
}
__device__ __forceinline__ unsigned short f2bf(float f) {
  union { float f; unsigned int u; } c;
  c.f = f;
  unsigned int u = c.u;
  u += 0x7fffu + ((u >> 16) & 1u);
  return (unsigned short)(u >> 16);
}

// ---------------- RMSNorm: f32 [rows][1024] -> bf16, block=256, grid=rows ----
__global__ __launch_bounds__(256) void k_rmsnorm(const float* __restrict__ x,
                                                 const float* __restrict__ w,
                                                 bf16* __restrict__ out) {
  const int row = blockIdx.x;
  const int t = threadIdx.x;
  float4 v = reinterpret_cast<const float4*>(x + (size_t)row * 1024)[t];
  float ss = v.x * v.x + v.y * v.y + v.z * v.z + v.w * v.w;
#pragma unroll
  for (int o = 32; o > 0; o >>= 1) ss += __shfl_xor(ss, o, 64);
  __shared__ float red[4];
  if ((t & 63) == 0) red[t >> 6] = ss;
  __syncthreads();
  float tot = red[0] + red[1] + red[2] + red[3];
  float sc = rsqrtf(tot * (1.f / 1024.f) + 1e-5f);
  float4 wv = reinterpret_cast<const float4*>(w)[t];
  ushort4 o4;
  o4.x = f2bf(v.x * sc * wv.x);
  o4.y = f2bf(v.y * sc * wv.y);
  o4.z = f2bf(v.z * sc * wv.z);
  o4.w = f2bf(v.w * sc * wv.w);
  reinterpret_cast<ushort4*>(out + (size_t)row * 1024)[t] = o4;
}

// ------------- Weight transpose+convert: f32 [R][C] -> bf16 [C][R] ----------
__global__ __launch_bounds__(256) void k_transpose_w(const float* __restrict__ W,
                                                     bf16* __restrict__ WT,
                                                     int R, int C) {
  __shared__ float tile[32][33];
  const int bx = blockIdx.x * 32;  // C
  const int by = blockIdx.y * 32;  // R
  const int tx = threadIdx.x, ty = threadIdx.y;  // (32,8)
#pragma unroll
  for (int i = 0; i < 4; i++)
    tile[ty + i * 8][tx] = W[(size_t)(by + ty + i * 8) * C + bx + tx];
  __syncthreads();
  unsigned short* WTu = (unsigned short*)WT;
#pragma unroll
  for (int i = 0; i < 4; i++)
    WTu[(size_t)(bx + ty + i * 8) * R + by + tx] = f2bf(tile[tx][ty + i * 8]);
}

// ------------- V transpose: qkv v-slice [4096][128] -> VT[bh][128][4096] ----
__global__ __launch_bounds__(256) void k_transpose_v(const bf16* __restrict__ qkv,
                                                     bf16* __restrict__ VT) {
  __shared__ unsigned short tile[32][33];
  const int bh = blockIdx.z, bb = bh >> 3, hh = bh & 7;
  const int dv0 = blockIdx.x * 32;   // 0..96
  const int t0 = blockIdx.y * 32;    // 0..4064
  const int tx = threadIdx.x, ty = threadIdx.y;  // (32,8)
  const unsigned short* vin = (const unsigned short*)qkv +
      (size_t)bb * 4096 * 3072 + 2048 + hh * 128;
#pragma unroll
  for (int i = 0; i < 4; i++)
    tile[ty + i * 8][tx] = vin[(size_t)(t0 + ty + i * 8) * 3072 + dv0 + tx];
  __syncthreads();
  unsigned short* vo = (unsigned short*)VT + (size_t)bh * 524288;
#pragma unroll
  for (int i = 0; i < 4; i++)
    vo[(size_t)(dv0 + ty + i * 8) * 4096 + t0 + tx] = tile[tx][ty + i * 8];
}

// ---------------- GEMM: C[M,N] = A[M,K](bf16) x BT[N,K](bf16) ----------------
// 128x128 tile, BK=64, 256 thr (4 waves, 2x2 of 64x64), mfma 16x16x32 bf16.
// EPI: 0 = store bf16; 1 = f32 store + residual add; 2 = silu(existing)*acc.
template <int EPI>
__global__ __launch_bounds__(256) void k_gemm(const bf16* __restrict__ A, int lda,
                                              const bf16* __restrict__ BT,
                                              const float* __restrict__ res,
                                              void* __restrict__ Cout,
                                              int N, int K) {
  constexpr int BK = 64;
  __shared__ __align__(16) unsigned short As[128][BK + 8];
  __shared__ __align__(16) unsigned short Bs[128][BK + 8];
  const int bm = blockIdx.y * 128, bn = blockIdx.x * 128;
  const int t = threadIdx.x;
  const int wid = t >> 6, lane = t & 63;
  const int wm = (wid >> 1) * 64, wn = (wid & 1) * 64;
  const int lm = lane & 15, kg = lane >> 4;

  const unsigned short* Ab = (const unsigned short*)A;
  const unsigned short* Bb = (const unsigned short*)BT;

  f32x4 acc[4][4] = {};
  uint4 areg[4], breg[4];
  const int r0 = t >> 3;           // + i*32
  const int c8 = (t & 7) << 3;     // element col within BK

#pragma unroll
  for (int i = 0; i < 4; i++) {
    areg[i] = *reinterpret_cast<const uint4*>(Ab + (size_t)(bm + r0 + i * 32) * lda + c8);
    breg[i] = *reinterpret_cast<const uint4*>(Bb + (size_t)(bn + r0 + i * 32) * K + c8);
  }
  const int NT = K / BK;
  for (int kt = 0; kt < NT; kt++) {
    __syncthreads();
#pragma unroll
    for (int i = 0; i < 4; i++) {
      *reinterpret_cast<uint4*>(&As[r0 + i * 32][c8]) = areg[i];
      *reinterpret_cast<uint4*>(&Bs[r0 + i * 32][c8]) = breg[i];
    }
    __syncthreads();
    if (kt + 1 < NT) {
      const int ko = (kt + 1) * BK;
#pragma unroll
      for (int i = 0; i < 4; i++) {
        areg[i] = *reinterpret_cast<const uint4*>(Ab + (size_t)(bm + r0 + i * 32) * lda + ko + c8);
        breg[i] = *reinterpret_cast<const uint4*>(Bb + (size_t)(bn + r0 + i * 32) * K + ko + c8);
      }
    }
#pragma unroll
    for (int kk = 0; kk < 2; kk++) {
      Frag af[4], bfr[4];
#pragma unroll
      for (int i = 0; i < 4; i++) {
        af[i].u = *reinterpret_cast<const uint4*>(&As[wm + i * 16 + lm][kk * 32 + kg * 8]);
        bfr[i].u = *reinterpret_cast<const uint4*>(&Bs[wn + i * 16 + lm][kk * 32 + kg * 8]);
      }
#pragma unroll
      for (int mi = 0; mi < 4; mi++)
#pragma unroll
        for (int ni = 0; ni < 4; ni++)
          acc[mi][ni] = __builtin_amdgcn_mfma_f32_16x16x32_bf16(af[mi].b, bfr[ni].b,
                                                                acc[mi][ni], 0, 0, 0);
    }
  }
  // epilogue: C row = bm+wm+mi*16+kg*4+r ; col = bn+wn+ni*16+lm
#pragma unroll
  for (int mi = 0; mi < 4; mi++) {
#pragma unroll
    for (int r = 0; r < 4; r++) {
      const int row = bm + wm + mi * 16 + kg * 4 + r;
#pragma unroll
      for (int ni = 0; ni < 4; ni++) {
        const int col = bn + wn + ni * 16 + lm;
        float v = acc[mi][ni][r];
        const size_t o = (size_t)row * N + col;
        if constexpr (EPI == 0) {
          ((unsigned short*)Cout)[o] = f2bf(v);
        } else if constexpr (EPI == 1) {
          ((float*)Cout)[o] = v + res[o];
        } else {
          unsigned short* cp = (unsigned short*)Cout;
          float g = bf2f(cp[o]);
          float sg = g / (1.f + __expf(-g));
          cp[o] = f2bf(sg * v);
        }
      }
    }
  }
}

// -------- K_A: per-(b,h,chunk) GT = (k^T v)^T = v^T k. grid=512, 256 thr ----
// VALU f32; thread fast axis = dk so GT writes are coalesced float4.
__global__ __launch_bounds__(256) void k_chunk_kv(const bf16* __restrict__ qkv,
                                                  float* __restrict__ G) {
  __shared__ __align__(16) unsigned short ks[128][128];
  __shared__ __align__(16) unsigned short vs[128][128];
  const int idx = blockIdx.x;
  const int cc = idx & 31, bh = idx >> 5, bb = bh >> 3, hh = bh & 7;
  const unsigned short* qkvu = (const unsigned short*)qkv;
  const unsigned short* kp = qkvu + (size_t)(bb * 4096 + cc * 128) * 3072 + 1024 + hh * 128;
  const unsigned short* vp = kp + 1024;
  const int t = threadIdx.x;
#pragma unroll
  for (int i = 0; i < 8; i++) {
    int ch = t + i * 256;
    int r = ch >> 4, c8 = (ch & 15) << 3;
    *(uint4*)&ks[r][c8] = *(const uint4*)(kp + (size_t)r * 3072 + c8);
    *(uint4*)&vs[r][c8] = *(const uint4*)(vp + (size_t)r * 3072 + c8);
  }
  __syncthreads();
  const int dv0 = (t >> 4) * 8, dk0 = (t & 15) * 8;  // GT rows dv, cols dk
  float acc[8][8] = {};
  for (int j = 0; j < 128; j++) {
    Frag kf, vf;
    vf.u = *(const uint4*)&vs[j][dv0];
    kf.u = *(const uint4*)&ks[j][dk0];
    float kx[8], vx[8];
#pragma unroll
    for (int a = 0; a < 8; a++) { kx[a] = bf2f(kf.s[a]); vx[a] = bf2f(vf.s[a]); }
#pragma unroll
    for (int a = 0; a < 8; a++)
#pragma unroll
      for (int b2 = 0; b2 < 8; b2++) acc[a][b2] += vx[a] * kx[b2];
  }
  float* Gp = G + (size_t)idx * 16384;
#pragma unroll
  for (int a = 0; a < 8; a++)
#pragma unroll
    for (int b2 = 0; b2 < 8; b2 += 4) {
      float4 w4 = make_float4(acc[a][b2], acc[a][b2 + 1], acc[a][b2 + 2], acc[a][b2 + 3]);
      *(float4*)(Gp + (size_t)(dv0 + a) * 128 + dk0 + b2) = w4;
    }
}

// -------- K_B: exclusive prefix over chunks -> ST bf16. grid=1024 -----------
__global__ __launch_bounds__(256) void k_prefix(const float* __restrict__ G,
                                                bf16* __restrict__ S) {
  const size_t gid = (size_t)blockIdx.x * 256 + threadIdx.x;
  const size_t bh = gid >> 14, e = gid & 16383;
  const float* gp = G + (bh << 5) * 16384 + e;
  unsigned short* sp = (unsigned short*)S + (bh << 5) * 16384 + e;
  float run = 0.f;
  for (int c2 = 0; c2 < 32; c2++) {
    sp[(size_t)c2 << 14] = f2bf(run);
    run += gp[(size_t)c2 << 14];
  }
}

// -------- K_C: MFMA fused chunk attention + per-head RMSNorm ----------------
// grid=512, 256 thr (4 waves, 2x2 quadrants of 64x64).
// P = tril(Q K^T); O = P V + Q S; o = rmsnorm_row(O)*nw -> A2 bf16.
__global__ __launch_bounds__(256) void k_attn2(const bf16* __restrict__ qkv,
                                               const bf16* __restrict__ VT,
                                               const bf16* __restrict__ ST,
                                               const float* __restrict__ nw,
                                               bf16* __restrict__ A2) {
  __shared__ __align__(16) unsigned short Qs[128][136];
  __shared__ __align__(16) unsigned short Ks[128][136];  // -> Ps -> Os
  __shared__ __align__(16) unsigned short Bs[128][136];  // VT tile -> ST tile
  __shared__ float red[128][2];

  const int idx = blockIdx.x;
  const int cc = idx & 31, bh = idx >> 5, bb = bh >> 3, hh = bh & 7;
  const size_t rowbase = (size_t)(bb * 4096 + cc * 128);
  const unsigned short* qp = (const unsigned short*)qkv + rowbase * 3072 + hh * 128;
  const unsigned short* kp = qp + 1024;
  const unsigned short* vtp = (const unsigned short*)VT + (size_t)bh * 524288 + cc * 128;
  const unsigned short* stp = (const unsigned short*)ST + ((size_t)idx << 14);

  const int t = threadIdx.x;
  const int wid = t >> 6, lane = t & 63;
  const int wm = (wid >> 1) * 64, wn = (wid & 1) * 64;
  const int lm = lane & 15, kg = lane >> 4;
  const int sr = t >> 4;          // staging row base (+= 16)
  const int sc = (t & 15) << 3;   // staging col (shorts)

  // stage Q, K, VT-chunk
#pragma unroll
  for (int i = 0; i < 8; i++) {
    int r = sr + i * 16;
    *(uint4*)&Qs[r][sc] = *(const uint4*)(qp + (size_t)r * 3072 + sc);
    *(uint4*)&Ks[r][sc] = *(const uint4*)(kp + (size_t)r * 3072 + sc);
    *(uint4*)&Bs[r][sc] = *(const uint4*)(vtp + (size_t)r * 4096 + sc);
  }
  __syncthreads();

  // phase 1: P = Q K^T (A=Qs rows i, BT=Ks rows j, contract d)
  f32x4 acc[4][4] = {};
#pragma unroll
  for (int kk = 0; kk < 4; kk++) {
    Frag af[4], bfr[4];
#pragma unroll
    for (int i = 0; i < 4; i++) {
      af[i].u = *(const uint4*)&Qs[wm + i * 16 + lm][kk * 32 + kg * 8];
      bfr[i].u = *(const uint4*)&Ks[wn + i * 16 + lm][kk * 32 + kg * 8];
    }
#pragma unroll
    for (int mi = 0; mi < 4; mi++)
#pragma unroll
      for (int ni = 0; ni < 4; ni++)
        acc[mi][ni] = __builtin_amdgcn_mfma_f32_16x16x32_bf16(af[mi].b, bfr[ni].b,
                                                              acc[mi][ni], 0, 0, 0);
  }
  __syncthreads();  // everyone done reading Ks

  // masked P -> bf16 into Ks (now Ps). D layout: row=kg*4+r, col=lm.
#pragma unroll
  for (int mi = 0; mi < 4; mi++)
#pragma unroll
    for (int r = 0; r < 4; r++) {
      const int gi = wm + mi * 16 + kg * 4 + r;
#pragma unroll
      for (int ni = 0; ni < 4; ni++) {
        const int gj = wn + ni * 16 + lm;
        Ks[gi][gj] = f2bf(gj <= gi ? acc[mi][ni][r] : 0.f);
      }
    }
  __syncthreads();

  // phase 2a: O = P V  (A=Ps rows i cols j; BT=Bs rows dv cols j)
  f32x4 oa[4][4] = {};
#pragma unroll
  for (int kk = 0; kk < 4; kk++) {
    Frag af[4], bfr[4];
#pragma unroll
    for (int i = 0; i < 4; i++) {
      af[i].u = *(const uint4*)&Ks[wm + i * 16 + lm][kk * 32 + kg * 8];
      bfr[i].u = *(const uint4*)&Bs[wn + i * 16 + lm][kk * 32 + kg * 8];
    }
#pragma unroll
    for (int mi = 0; mi < 4; mi++)
#pragma unroll
      for (int ni = 0; ni < 4; ni++)
        oa[mi][ni] = __builtin_amdgcn_mfma_f32_16x16x32_bf16(af[mi].b, bfr[ni].b,
                                                             oa[mi][ni], 0, 0, 0);
  }
  __syncthreads();  // done reading Bs(VT)

  // stage ST chunk into Bs
#pragma unroll
  for (int i = 0; i < 8; i++) {
    int r = sr + i * 16;
    *(uint4*)&Bs[r][sc] = *(const uint4*)(stp + (size_t)r * 128 + sc);
  }
  __syncthreads();

  // phase 2b: O += Q S  (A=Qs rows i cols dk; BT=Bs rows dv cols dk)
#pragma unroll
  for (int kk = 0; kk < 4; kk++) {
    Frag af[4], bfr[4];
#pragma unroll
    for (int i = 0; i < 4; i++) {
      af[i].u = *(const uint4*)&Qs[wm + i * 16 + lm][kk * 32 + kg * 8];
      bfr[i].u = *(const uint4*)&Bs[wn + i * 16 + lm][kk * 32 + kg * 8];
    }
#pragma unroll
    for (int mi = 0; mi < 4; mi++)
#pragma unroll
      for (int ni = 0; ni < 4; ni++)
        oa[mi][ni] = __builtin_amdgcn_mfma_f32_16x16x32_bf16(af[mi].b, bfr[ni].b,
                                                             oa[mi][ni], 0, 0, 0);
  }

  // per-row sum of squares over DV=128: lane-group reduce + cross-wave via LDS
#pragma unroll
  for (int mi = 0; mi < 4; mi++)
#pragma unroll
    for (int r = 0; r < 4; r++) {
      float ss = 0.f;
#pragma unroll
      for (int ni = 0; ni < 4; ni++) ss += oa[mi][ni][r] * oa[mi][ni][r];
      ss += __shfl_xor(ss, 1, 64);
      ss += __shfl_xor(ss, 2, 64);
      ss += __shfl_xor(ss, 4, 64);
      ss += __shfl_xor(ss, 8, 64);
      if (lm == 0) red[wm + mi * 16 + kg * 4 + r][wid & 1] = ss;
    }
  __syncthreads();

  // scale, weight, write bf16 into Ks (now Os)
#pragma unroll
  for (int mi = 0; mi < 4; mi++)
#pragma unroll
    for (int r = 0; r < 4; r++) {
      const int gi = wm + mi * 16 + kg * 4 + r;
      const float tot = red[gi][0] + red[gi][1];
      const float scl = rsqrtf(tot * (1.f / 128.f) + 1e-5f);
#pragma unroll
      for (int ni = 0; ni < 4; ni++) {
        const int gj = wn + ni * 16 + lm;
        Ks[gi][gj] = f2bf(oa[mi][ni][r] * scl * nw[gj]);
      }
    }
  __syncthreads();

  // coalesced output copy
  unsigned short* A2u = (unsigned short*)A2;
#pragma unroll
  for (int i = 0; i < 8; i++) {
    int r = sr + i * 16;
    *(uint4*)(A2u + (rowbase + r) * 1024 + hh * 128 + sc) = *(const uint4*)&Ks[r][sc];
  }
}

// ---------------------------------------------------------------------------
extern "C" void kernel_launch(void* const* d_in, const int* in_sizes, int n_in,
                              void* d_out, int out_size, void* d_ws, size_t ws_size,
                              hipStream_t stream) {
  const float* x = (const float*)d_in[0];
  const float* anw = (const float*)d_in[1];
  const float* Wq = (const float*)d_in[2];
  const float* Wk = (const float*)d_in[3];
  const float* Wv = (const float*)d_in[4];
  const float* Wo = (const float*)d_in[5];
  const float* onw = (const float*)d_in[6];
  const float* mnw = (const float*)d_in[7];
  const float* Wg = (const float*)d_in[8];
  const float* Wu = (const float*)d_in[9];
  const float* Wd = (const float*)d_in[10];
  float* out = (float*)d_out;

  char* base = (char*)d_ws;
  size_t off = 0;
  auto alloc = [&](size_t bytes) -> char* {
    char* q = base + off;
    off += (bytes + 255) & ~(size_t)255;
    return q;
  };
  bf16* WqkvT = (bf16*)alloc(3072ll * 1024 * 2);   // [3072][1024]
  bf16* WoT   = (bf16*)alloc(1024ll * 1024 * 2);   // [1024][1024]
  bf16* WguT  = (bf16*)alloc(8192ll * 1024 * 2);   // [8192][1024] (gate|up)
  bf16* WdT   = (bf16*)alloc(1024ll * 4096 * 2);   // [1024][4096]
  bf16* h     = (bf16*)alloc(8192ll * 1024 * 2);   // normed acts / A2
  float* x1   = (float*)alloc(8192ll * 1024 * 4);  // residual stream after attn
  char* pool  = alloc(8192ll * 3072 * 2 + 16ll * 32 * 16384 * 4 +
                      16ll * 32 * 16384 * 2 + 16ll * 128 * 4096 * 2);
  bf16* qkv = (bf16*)pool;                                        // 50.3 MB
  float* G  = (float*)(pool + 8192ll * 3072 * 2);                 // 33.6 MB (GT)
  bf16* S   = (bf16*)(pool + 8192ll * 3072 * 2 + 16ll * 32 * 16384 * 4);  // 16.8 MB (ST)
  bf16* VT  = (bf16*)(pool + 8192ll * 3072 * 2 + 16ll * 32 * 16384 * 4 +
                      16ll * 32 * 16384 * 2);                     // 16.8 MB
  bf16* gate = (bf16*)pool;  // phase 2 reuse: [8192][4096] = 67 MB

  const dim3 tb32(32, 8);
  // weight transpose+convert
  k_transpose_w<<<dim3(32, 32), tb32, 0, stream>>>(Wq, WqkvT, 1024, 1024);
  k_transpose_w<<<dim3(32, 32), tb32, 0, stream>>>(Wk, WqkvT + 1024ll * 1024, 1024, 1024);
  k_transpose_w<<<dim3(32, 32), tb32, 0, stream>>>(Wv, WqkvT + 2048ll * 1024, 1024, 1024);
  k_transpose_w<<<dim3(32, 32), tb32, 0, stream>>>(Wo, WoT, 1024, 1024);
  k_transpose_w<<<dim3(128, 32), tb32, 0, stream>>>(Wg, WguT, 1024, 4096);
  k_transpose_w<<<dim3(128, 32), tb32, 0, stream>>>(Wu, WguT + 4096ll * 1024, 1024, 4096);
  k_transpose_w<<<dim3(32, 128), tb32, 0, stream>>>(Wd, WdT, 4096, 1024);

  // attn sub-block
  k_rmsnorm<<<8192, 256, 0, stream>>>(x, anw, h);
  k_gemm<0><<<dim3(24, 64), 256, 0, stream>>>(h, 1024, WqkvT, nullptr, qkv, 3072, 1024);
  k_transpose_v<<<dim3(4, 128, 16), tb32, 0, stream>>>(qkv, VT);
  k_chunk_kv<<<512, 256, 0, stream>>>(qkv, G);
  k_prefix<<<1024, 256, 0, stream>>>(G, S);
  k_attn2<<<512, 256, 0, stream>>>(qkv, VT, S, onw, h);  // h = normed o
  k_gemm<1><<<dim3(8, 64), 256, 0, stream>>>(h, 1024, WoT, x, x1, 1024, 1024);

  // mlp sub-block
  k_rmsnorm<<<8192, 256, 0, stream>>>(x1, mnw, h);
  k_gemm<0><<<dim3(32, 64), 256, 0, stream>>>(h, 1024, WguT, nullptr, gate, 4096, 1024);
  k_gemm<2><<<dim3(32, 64), 256, 0, stream>>>(h, 1024, WguT + 4096ll * 1024, nullptr, gate, 4096, 1024);
  k_gemm<1><<<dim3(8, 64), 256, 0, stream>>>(gate, 4096, WdT, x1, out, 1024, 4096);
}

// Round 3
// 580.311 us; speedup vs baseline: 8.4218x; 2.5663x over previous
//
#include <hip/hip_runtime.h>
#include <hip/hip_bf16.h>
#include <stdint.h>

// LinearAttentionBlock: B=2,T=4096,D=1024,H=8,DK=DV=128,INTER=4096,CHUNK=128
// Round 3: m97-structure GEMM (global_load_lds w=16, linear LDS, 2-barrier),
// coalesced LDS-routed epilogues (kills 15x write amplification), silu fused
// into up-GEMM epilogue (EPI=3), XCD-swizzled grids.

typedef __hip_bfloat16 bf16;
typedef __bf16 bf16x8 __attribute__((ext_vector_type(8)));
typedef float f32x4 __attribute__((ext_vector_type(4)));

union Frag {
  uint4 u;
  bf16x8 b;
  unsigned short s[8];
};

__device__ __forceinline__ float bf2f(unsigned short v) {
  union { unsigned int u; float f; } c;
  c.u = (unsigned int)v << 16;
  return c.f;
}
__device__ __forceinline__ unsigned short f2bf(float f) {
  union { float f; unsigned int u; } c;
  c.f = f;
  unsigned int u = c.u;
  u += 0x7fffu + ((u >> 16) & 1u);
  return (unsigned short)(u >> 16);
}

__device__ __forceinline__ void gload16(const unsigned short* g, unsigned short* l) {
  __builtin_amdgcn_global_load_lds(
      (const __attribute__((address_space(1))) unsigned int*)g,
      (__attribute__((address_space(3))) unsigned int*)l, 16, 0, 0);
}

// ---------------- RMSNorm: f32 [rows][1024] -> bf16, block=256, grid=rows ----
__global__ __launch_bounds__(256) void k_rmsnorm(const float* __restrict__ x,
                                                 const float* __restrict__ w,
                                                 bf16* __restrict__ out) {
  const int row = blockIdx.x;
  const int t = threadIdx.x;
  float4 v = reinterpret_cast<const float4*>(x + (size_t)row * 1024)[t];
  float ss = v.x * v.x + v.y * v.y + v.z * v.z + v.w * v.w;
#pragma unroll
  for (int o = 32; o > 0; o >>= 1) ss += __shfl_xor(ss, o, 64);
  __shared__ float red[4];
  if ((t & 63) == 0) red[t >> 6] = ss;
  __syncthreads();
  float tot = red[0] + red[1] + red[2] + red[3];
  float sc = rsqrtf(tot * (1.f / 1024.f) + 1e-5f);
  float4 wv = reinterpret_cast<const float4*>(w)[t];
  ushort4 o4;
  o4.x = f2bf(v.x * sc * wv.x);
  o4.y = f2bf(v.y * sc * wv.y);
  o4.z = f2bf(v.z * sc * wv.z);
  o4.w = f2bf(v.w * sc * wv.w);
  reinterpret_cast<ushort4*>(out + (size_t)row * 1024)[t] = o4;
}

// ------------- Weight transpose+convert: f32 [R][C] -> bf16 [C][R] ----------
__global__ __launch_bounds__(256) void k_transpose_w(const float* __restrict__ W,
                                                     bf16* __restrict__ WT,
                                                     int R, int C) {
  __shared__ float tile[32][33];
  const int bx = blockIdx.x * 32;  // C
  const int by = blockIdx.y * 32;  // R
  const int tx = threadIdx.x, ty = threadIdx.y;  // (32,8)
#pragma unroll
  for (int i = 0; i < 4; i++)
    tile[ty + i * 8][tx] = W[(size_t)(by + ty + i * 8) * C + bx + tx];
  __syncthreads();
  unsigned short* WTu = (unsigned short*)WT;
#pragma unroll
  for (int i = 0; i < 4; i++)
    WTu[(size_t)(bx + ty + i * 8) * R + by + tx] = f2bf(tile[tx][ty + i * 8]);
}

// ------------- V transpose: qkv v-slice [4096][128] -> VT[bh][128][4096] ----
__global__ __launch_bounds__(256) void k_transpose_v(const bf16* __restrict__ qkv,
                                                     bf16* __restrict__ VT) {
  __shared__ unsigned short tile[32][33];
  const int bh = blockIdx.z, bb = bh >> 3, hh = bh & 7;
  const int dv0 = blockIdx.x * 32;   // 0..96
  const int t0 = blockIdx.y * 32;    // 0..4064
  const int tx = threadIdx.x, ty = threadIdx.y;  // (32,8)
  const unsigned short* vin = (const unsigned short*)qkv +
      (size_t)bb * 4096 * 3072 + 2048 + hh * 128;
#pragma unroll
  for (int i = 0; i < 4; i++)
    tile[ty + i * 8][tx] = vin[(size_t)(t0 + ty + i * 8) * 3072 + dv0 + tx];
  __syncthreads();
  unsigned short* vo = (unsigned short*)VT + (size_t)bh * 524288;
#pragma unroll
  for (int i = 0; i < 4; i++)
    vo[(size_t)(dv0 + ty + i * 8) * 4096 + t0 + tx] = tile[tx][ty + i * 8];
}

// ---------------- GEMM: C[M,N] = A[M,K](bf16) x BT[N,K](bf16) ----------------
// m97 structure: 128x128 tile, BK=64, global_load_lds w=16 into linear LDS,
// 2 barriers/K-step, LDS-routed coalesced epilogue.
// EPI: 0 = bf16 store; 1 = f32 store + residual; 3 = Cout=silu(Cout)*acc bf16.
template <int EPI>
__global__ __launch_bounds__(256) void k_gemm(const bf16* __restrict__ A, int lda,
                                              const bf16* __restrict__ BT,
                                              const float* __restrict__ res,
                                              void* __restrict__ Cout,
                                              int N, int K) {
  constexpr int BK = 64;
  __shared__ __align__(16) unsigned short lds[16384];  // A:[0,8192) B:[8192,16384)

  // XCD-aware bijective block swizzle (nwg always divisible by 8)
  const int gx = gridDim.x;
  const int nwg = gx * gridDim.y;
  const int lin = blockIdx.y * gx + blockIdx.x;
  const int swz = (lin & 7) * (nwg >> 3) + (lin >> 3);
  const int bm = (swz / gx) * 128, bn = (swz % gx) * 128;

  const int t = threadIdx.x;
  const int wid = t >> 6, lane = t & 63;
  const int wm = (wid >> 1) * 64, wn = (wid & 1) * 64;
  const int lm = lane & 15, kg = lane >> 4;
  const int wrow = wid * 32;                 // staging rows for this wave
  const int srow = lane >> 3, scol = (lane & 7) << 3;

  const unsigned short* Ab = (const unsigned short*)A;
  const unsigned short* Bb = (const unsigned short*)BT;

  f32x4 acc[4][4] = {};
  const int NT = K / BK;
  for (int kt = 0; kt < NT; kt++) {
    const int ko = kt * BK;
#pragma unroll
    for (int i = 0; i < 4; i++) {
      gload16(Ab + (size_t)(bm + wrow + i * 8 + srow) * lda + ko + scol,
              &lds[(wrow + i * 8) * 64]);
      gload16(Bb + (size_t)(bn + wrow + i * 8 + srow) * K + ko + scol,
              &lds[8192 + (wrow + i * 8) * 64]);
    }
    __syncthreads();  // drains vmcnt -> LDS tiles ready
#pragma unroll
    for (int kk = 0; kk < 2; kk++) {
      Frag af[4], bfr[4];
#pragma unroll
      for (int i = 0; i < 4; i++) {
        af[i].u = *(const uint4*)&lds[(wm + i * 16 + lm) * 64 + kk * 32 + kg * 8];
        bfr[i].u = *(const uint4*)&lds[8192 + (wn + i * 16 + lm) * 64 + kk * 32 + kg * 8];
      }
#pragma unroll
      for (int mi = 0; mi < 4; mi++)
#pragma unroll
        for (int ni = 0; ni < 4; ni++)
          acc[mi][ni] = __builtin_amdgcn_mfma_f32_16x16x32_bf16(af[mi].b, bfr[ni].b,
                                                                acc[mi][ni], 0, 0, 0);
    }
    __syncthreads();  // all waves done reading before next stage overwrites
  }

  // ---- epilogue: route through LDS for coalesced wide stores ----
  if constexpr (EPI == 1) {
    float* Ef = (float*)lds;  // [64][128]
    float* Co = (float*)Cout;
#pragma unroll
    for (int p = 0; p < 2; p++) {
      __syncthreads();
      if ((wm >> 6) == p) {
#pragma unroll
        for (int mi = 0; mi < 4; mi++)
#pragma unroll
          for (int r = 0; r < 4; r++)
#pragma unroll
            for (int ni = 0; ni < 4; ni++)
              Ef[(mi * 16 + kg * 4 + r) * 128 + wn + ni * 16 + lm] = acc[mi][ni][r];
      }
      __syncthreads();
#pragma unroll
      for (int j = 0; j < 8; j++) {
        const int idx = t + j * 256;
        const int row = idx >> 5, c4 = (idx & 31) << 2;
        const size_t o = (size_t)(bm + p * 64 + row) * N + bn + c4;
        float4 v = *(const float4*)&Ef[row * 128 + c4];
        float4 rv = *(const float4*)&res[o];
        v.x += rv.x; v.y += rv.y; v.z += rv.z; v.w += rv.w;
        *(float4*)&Co[o] = v;
      }
    }
  } else {
    // acc -> [128][128] bf16 in LDS
#pragma unroll
    for (int mi = 0; mi < 4; mi++)
#pragma unroll
      for (int r = 0; r < 4; r++)
#pragma unroll
        for (int ni = 0; ni < 4; ni++)
          lds[(wm + mi * 16 + kg * 4 + r) * 128 + wn + ni * 16 + lm] =
              f2bf(acc[mi][ni][r]);
    __syncthreads();
    unsigned short* Cu = (unsigned short*)Cout;
#pragma unroll
    for (int j = 0; j < 8; j++) {
      const int row = (t >> 4) + j * 16, seg = (t & 15) << 3;
      const size_t o = (size_t)(bm + row) * N + bn + seg;
      if constexpr (EPI == 0) {
        *(uint4*)(Cu + o) = *(const uint4*)&lds[row * 128 + seg];
      } else {  // EPI == 3: Cout = silu(Cout) * acc
        Frag uf, gf, rr;
        uf.u = *(const uint4*)&lds[row * 128 + seg];
        gf.u = *(const uint4*)(Cu + o);
#pragma unroll
        for (int a = 0; a < 8; a++) {
          float g = bf2f(gf.s[a]);
          float uu = bf2f(uf.s[a]);
          float sg = g / (1.f + __expf(-g));
          rr.s[a] = f2bf(sg * uu);
        }
        *(uint4*)(Cu + o) = rr.u;
      }
    }
  }
}

// -------- K_A: per-(b,h,chunk) GT = (k^T v)^T = v^T k. grid=512, 256 thr ----
__global__ __launch_bounds__(256) void k_chunk_kv(const bf16* __restrict__ qkv,
                                                  float* __restrict__ G) {
  __shared__ __align__(16) unsigned short ks[128][128];
  __shared__ __align__(16) unsigned short vs[128][128];
  const int idx = blockIdx.x;
  const int cc = idx & 31, bh = idx >> 5, bb = bh >> 3, hh = bh & 7;
  const unsigned short* qkvu = (const unsigned short*)qkv;
  const unsigned short* kp = qkvu + (size_t)(bb * 4096 + cc * 128) * 3072 + 1024 + hh * 128;
  const unsigned short* vp = kp + 1024;
  const int t = threadIdx.x;
#pragma unroll
  for (int i = 0; i < 8; i++) {
    int ch = t + i * 256;
    int r = ch >> 4, c8 = (ch & 15) << 3;
    *(uint4*)&ks[r][c8] = *(const uint4*)(kp + (size_t)r * 3072 + c8);
    *(uint4*)&vs[r][c8] = *(const uint4*)(vp + (size_t)r * 3072 + c8);
  }
  __syncthreads();
  const int dv0 = (t >> 4) * 8, dk0 = (t & 15) * 8;  // GT rows dv, cols dk
  float acc[8][8] = {};
  for (int j = 0; j < 128; j++) {
    Frag kf, vf;
    vf.u = *(const uint4*)&vs[j][dv0];
    kf.u = *(const uint4*)&ks[j][dk0];
    float kx[8], vx[8];
#pragma unroll
    for (int a = 0; a < 8; a++) { kx[a] = bf2f(kf.s[a]); vx[a] = bf2f(vf.s[a]); }
#pragma unroll
    for (int a = 0; a < 8; a++)
#pragma unroll
      for (int b2 = 0; b2 < 8; b2++) acc[a][b2] += vx[a] * kx[b2];
  }
  float* Gp = G + (size_t)idx * 16384;
#pragma unroll
  for (int a = 0; a < 8; a++)
#pragma unroll
    for (int b2 = 0; b2 < 8; b2 += 4) {
      float4 w4 = make_float4(acc[a][b2], acc[a][b2 + 1], acc[a][b2 + 2], acc[a][b2 + 3]);
      *(float4*)(Gp + (size_t)(dv0 + a) * 128 + dk0 + b2) = w4;
    }
}

// -------- K_B: exclusive prefix over chunks -> ST bf16. grid=1024 -----------
__global__ __launch_bounds__(256) void k_prefix(const float* __restrict__ G,
                                                bf16* __restrict__ S) {
  const size_t gid = (size_t)blockIdx.x * 256 + threadIdx.x;
  const size_t bh = gid >> 14, e = gid & 16383;
  const float* gp = G + (bh << 5) * 16384 + e;
  unsigned short* sp = (unsigned short*)S + (bh << 5) * 16384 + e;
  float run = 0.f;
  for (int c2 = 0; c2 < 32; c2++) {
    sp[(size_t)c2 << 14] = f2bf(run);
    run += gp[(size_t)c2 << 14];
  }
}

// -------- K_C: MFMA fused chunk attention + per-head RMSNorm ----------------
__global__ __launch_bounds__(256) void k_attn2(const bf16* __restrict__ qkv,
                                               const bf16* __restrict__ VT,
                                               const bf16* __restrict__ ST,
                                               const float* __restrict__ nw,
                                               bf16* __restrict__ A2) {
  __shared__ __align__(16) unsigned short Qs[128][136];
  __shared__ __align__(16) unsigned short Ks[128][136];  // -> Ps -> Os
  __shared__ __align__(16) unsigned short Bs[128][136];  // VT tile -> ST tile
  __shared__ float red[128][2];

  const int idx = blockIdx.x;
  const int cc = idx & 31, bh = idx >> 5, bb = bh >> 3, hh = bh & 7;
  const size_t rowbase = (size_t)(bb * 4096 + cc * 128);
  const unsigned short* qp = (const unsigned short*)qkv + rowbase * 3072 + hh * 128;
  const unsigned short* kp = qp + 1024;
  const unsigned short* vtp = (const unsigned short*)VT + (size_t)bh * 524288 + cc * 128;
  const unsigned short* stp = (const unsigned short*)ST + ((size_t)idx << 14);

  const int t = threadIdx.x;
  const int wid = t >> 6, lane = t & 63;
  const int wm = (wid >> 1) * 64, wn = (wid & 1) * 64;
  const int lm = lane & 15, kg = lane >> 4;
  const int sr = t >> 4;          // staging row base (+= 16)
  const int sc = (t & 15) << 3;   // staging col (shorts)

#pragma unroll
  for (int i = 0; i < 8; i++) {
    int r = sr + i * 16;
    *(uint4*)&Qs[r][sc] = *(const uint4*)(qp + (size_t)r * 3072 + sc);
    *(uint4*)&Ks[r][sc] = *(const uint4*)(kp + (size_t)r * 3072 + sc);
    *(uint4*)&Bs[r][sc] = *(const uint4*)(vtp + (size_t)r * 4096 + sc);
  }
  __syncthreads();

  // phase 1: P = Q K^T
  f32x4 acc[4][4] = {};
#pragma unroll
  for (int kk = 0; kk < 4; kk++) {
    Frag af[4], bfr[4];
#pragma unroll
    for (int i = 0; i < 4; i++) {
      af[i].u = *(const uint4*)&Qs[wm + i * 16 + lm][kk * 32 + kg * 8];
      bfr[i].u = *(const uint4*)&Ks[wn + i * 16 + lm][kk * 32 + kg * 8];
    }
#pragma unroll
    for (int mi = 0; mi < 4; mi++)
#pragma unroll
      for (int ni = 0; ni < 4; ni++)
        acc[mi][ni] = __builtin_amdgcn_mfma_f32_16x16x32_bf16(af[mi].b, bfr[ni].b,
                                                              acc[mi][ni], 0, 0, 0);
  }
  __syncthreads();

  // masked P -> bf16 into Ks
#pragma unroll
  for (int mi = 0; mi < 4; mi++)
#pragma unroll
    for (int r = 0; r < 4; r++) {
      const int gi = wm + mi * 16 + kg * 4 + r;
#pragma unroll
      for (int ni = 0; ni < 4; ni++) {
        const int gj = wn + ni * 16 + lm;
        Ks[gi][gj] = f2bf(gj <= gi ? acc[mi][ni][r] : 0.f);
      }
    }
  __syncthreads();

  // phase 2a: O = P V
  f32x4 oa[4][4] = {};
#pragma unroll
  for (int kk = 0; kk < 4; kk++) {
    Frag af[4], bfr[4];
#pragma unroll
    for (int i = 0; i < 4; i++) {
      af[i].u = *(const uint4*)&Ks[wm + i * 16 + lm][kk * 32 + kg * 8];
      bfr[i].u = *(const uint4*)&Bs[wn + i * 16 + lm][kk * 32 + kg * 8];
    }
#pragma unroll
    for (int mi = 0; mi < 4; mi++)
#pragma unroll
      for (int ni = 0; ni < 4; ni++)
        oa[mi][ni] = __builtin_amdgcn_mfma_f32_16x16x32_bf16(af[mi].b, bfr[ni].b,
                                                             oa[mi][ni], 0, 0, 0);
  }
  __syncthreads();

  // stage ST chunk into Bs
#pragma unroll
  for (int i = 0; i < 8; i++) {
    int r = sr + i * 16;
    *(uint4*)&Bs[r][sc] = *(const uint4*)(stp + (size_t)r * 128 + sc);
  }
  __syncthreads();

  // phase 2b: O += Q S
#pragma unroll
  for (int kk = 0; kk < 4; kk++) {
    Frag af[4], bfr[4];
#pragma unroll
    for (int i = 0; i < 4; i++) {
      af[i].u = *(const uint4*)&Qs[wm + i * 16 + lm][kk * 32 + kg * 8];
      bfr[i].u = *(const uint4*)&Bs[wn + i * 16 + lm][kk * 32 + kg * 8];
    }
#pragma unroll
    for (int mi = 0; mi < 4; mi++)
#pragma unroll
      for (int ni = 0; ni < 4; ni++)
        oa[mi][ni] = __builtin_amdgcn_mfma_f32_16x16x32_bf16(af[mi].b, bfr[ni].b,
                                                             oa[mi][ni], 0, 0, 0);
  }

  // per-row sum of squares over DV=128
#pragma unroll
  for (int mi = 0; mi < 4; mi++)
#pragma unroll
    for (int r = 0; r < 4; r++) {
      float ss = 0.f;
#pragma unroll
      for (int ni = 0; ni < 4; ni++) ss += oa[mi][ni][r] * oa[mi][ni][r];
      ss += __shfl_xor(ss, 1, 64);
      ss += __shfl_xor(ss, 2, 64);
      ss += __shfl_xor(ss, 4, 64);
      ss += __shfl_xor(ss, 8, 64);
      if (lm == 0) red[wm + mi * 16 + kg * 4 + r][wid & 1] = ss;
    }
  __syncthreads();

#pragma unroll
  for (int mi = 0; mi < 4; mi++)
#pragma unroll
    for (int r = 0; r < 4; r++) {
      const int gi = wm + mi * 16 + kg * 4 + r;
      const float tot = red[gi][0] + red[gi][1];
      const float scl = rsqrtf(tot * (1.f / 128.f) + 1e-5f);
#pragma unroll
      for (int ni = 0; ni < 4; ni++) {
        const int gj = wn + ni * 16 + lm;
        Ks[gi][gj] = f2bf(oa[mi][ni][r] * scl * nw[gj]);
      }
    }
  __syncthreads();

  unsigned short* A2u = (unsigned short*)A2;
#pragma unroll
  for (int i = 0; i < 8; i++) {
    int r = sr + i * 16;
    *(uint4*)(A2u + (rowbase + r) * 1024 + hh * 128 + sc) = *(const uint4*)&Ks[r][sc];
  }
}

// ---------------------------------------------------------------------------
extern "C" void kernel_launch(void* const* d_in, const int* in_sizes, int n_in,
                              void* d_out, int out_size, void* d_ws, size_t ws_size,
                              hipStream_t stream) {
  const float* x = (const float*)d_in[0];
  const float* anw = (const float*)d_in[1];
  const float* Wq = (const float*)d_in[2];
  const float* Wk = (const float*)d_in[3];
  const float* Wv = (const float*)d_in[4];
  const float* Wo = (const float*)d_in[5];
  const float* onw = (const float*)d_in[6];
  const float* mnw = (const float*)d_in[7];
  const float* Wg = (const float*)d_in[8];
  const float* Wu = (const float*)d_in[9];
  const float* Wd = (const float*)d_in[10];
  float* out = (float*)d_out;

  char* base = (char*)d_ws;
  size_t off = 0;
  auto alloc = [&](size_t bytes) -> char* {
    char* q = base + off;
    off += (bytes + 255) & ~(size_t)255;
    return q;
  };
  bf16* WqkvT = (bf16*)alloc(3072ll * 1024 * 2);   // [3072][1024]
  bf16* WoT   = (bf16*)alloc(1024ll * 1024 * 2);   // [1024][1024]
  bf16* WguT  = (bf16*)alloc(8192ll * 1024 * 2);   // [8192][1024] (gate|up)
  bf16* WdT   = (bf16*)alloc(1024ll * 4096 * 2);   // [1024][4096]
  bf16* h     = (bf16*)alloc(8192ll * 1024 * 2);   // normed acts / A2
  float* x1   = (float*)alloc(8192ll * 1024 * 4);  // residual after attn
  char* pool  = alloc(8192ll * 3072 * 2 + 16ll * 32 * 16384 * 4 +
                      16ll * 32 * 16384 * 2 + 16ll * 128 * 4096 * 2);
  bf16* qkv = (bf16*)pool;                                        // 50.3 MB
  float* G  = (float*)(pool + 8192ll * 3072 * 2);                 // 33.6 MB (GT)
  bf16* S   = (bf16*)(pool + 8192ll * 3072 * 2 + 16ll * 32 * 16384 * 4);  // (ST)
  bf16* VT  = (bf16*)(pool + 8192ll * 3072 * 2 + 16ll * 32 * 16384 * 4 +
                      16ll * 32 * 16384 * 2);
  bf16* gate = (bf16*)pool;  // MLP phase reuse: [8192][4096] = 67 MB

  const dim3 tb32(32, 8);
  // weight transpose+convert
  k_transpose_w<<<dim3(32, 32), tb32, 0, stream>>>(Wq, WqkvT, 1024, 1024);
  k_transpose_w<<<dim3(32, 32), tb32, 0, stream>>>(Wk, WqkvT + 1024ll * 1024, 1024, 1024);
  k_transpose_w<<<dim3(32, 32), tb32, 0, stream>>>(Wv, WqkvT + 2048ll * 1024, 1024, 1024);
  k_transpose_w<<<dim3(32, 32), tb32, 0, stream>>>(Wo, WoT, 1024, 1024);
  k_transpose_w<<<dim3(128, 32), tb32, 0, stream>>>(Wg, WguT, 1024, 4096);
  k_transpose_w<<<dim3(128, 32), tb32, 0, stream>>>(Wu, WguT + 4096ll * 1024, 1024, 4096);
  k_transpose_w<<<dim3(32, 128), tb32, 0, stream>>>(Wd, WdT, 4096, 1024);

  // attn sub-block
  k_rmsnorm<<<8192, 256, 0, stream>>>(x, anw, h);
  k_gemm<0><<<dim3(24, 64), 256, 0, stream>>>(h, 1024, WqkvT, nullptr, qkv, 3072, 1024);
  k_transpose_v<<<dim3(4, 128, 16), tb32, 0, stream>>>(qkv, VT);
  k_chunk_kv<<<512, 256, 0, stream>>>(qkv, G);
  k_prefix<<<1024, 256, 0, stream>>>(G, S);
  k_attn2<<<512, 256, 0, stream>>>(qkv, VT, S, onw, h);  // h = normed o
  k_gemm<1><<<dim3(8, 64), 256, 0, stream>>>(h, 1024, WoT, x, x1, 1024, 1024);

  // mlp sub-block
  k_rmsnorm<<<8192, 256, 0, stream>>>(x1, mnw, h);
  k_gemm<0><<<dim3(32, 64), 256, 0, stream>>>(h, 1024, WguT, nullptr, gate, 4096, 1024);
  k_gemm<3><<<dim3(32, 64), 256, 0, stream>>>(h, 1024, WguT + 4096ll * 1024, nullptr, gate, 4096, 1024);
  k_gemm<1><<<dim3(8, 64), 256, 0, stream>>>(gate, 4096, WdT, x1, out, 1024, 4096);
}